// Round 4
// baseline (945.929 us; speedup 1.0000x reference)
//
#include <hip/hip_runtime.h>

// SwinJSCC encoder, 2 depths. I/O fp32; internal GEMM operands bf16; fp32 residual
// stream lives IN d_out. ws map: [0,32M) ybuf bf16 | [32M,160M) qkv bf16 (96MB used)
// then reused as h1 (128MB) | [160M,~164M) wT (bf16 transposed weights) + addv fp32.

typedef unsigned short bfraw;
typedef short s16x8 __attribute__((ext_vector_type(8)));
typedef short s16x4 __attribute__((ext_vector_type(4)));
typedef float f32x4 __attribute__((ext_vector_type(4)));

#define DEV static __device__ __forceinline__

DEV float b2f(int u){
  union { unsigned int i; float f; } x;
  x.i = ((unsigned int)u & 0xffffu) << 16;
  return x.f;
}
DEV unsigned short f2bbits(float f){
  union { float f; unsigned int i; } x; x.f = f;
  unsigned int i = x.i;
  unsigned int lsb = (i >> 16) & 1u;
  i += 0x7fffu + lsb;                 // round-to-nearest-even
  return (unsigned short)(i >> 16);
}

#define GLOAD_LDS16(g, l) __builtin_amdgcn_global_load_lds(                      \
    (const __attribute__((address_space(1))) void*)(g),                          \
    (__attribute__((address_space(3))) void*)(l), 16, 0, 0)

// ---------------- fp32 copy: x input -> residual stream (d_out) ----------------
__global__ void k_copy(const float* __restrict__ xin, float* __restrict__ xfp){
  size_t i = ((size_t)blockIdx.x * 256 + threadIdx.x) * 4;
  *(float4*)(xfp + i) = *(const float4*)(xin + i);
}

// ---------------- weight transpose+cast [K,N] fp32 -> [N,K] bf16 ----------------
__global__ void k_tr(const float* __restrict__ in, bfraw* __restrict__ out, int K, int N){
  int idx = blockIdx.x * 256 + threadIdx.x;
  if (idx >= K * N) return;
  int n = idx / K, k = idx - n * K;
  out[idx] = f2bbits(in[(size_t)k * N + n]);
}

// ---------------- LayerNorm over C=256 (fp32 in, bf16 out), one wave per row ----------------
__global__ __launch_bounds__(256) void k_ln(
    const float* __restrict__ x, const float* __restrict__ g,
    const float* __restrict__ b, bfraw* __restrict__ y)
{
  const int lane = threadIdx.x & 63, wv = threadIdx.x >> 6;
  const size_t row = (size_t)blockIdx.x * 4 + wv;
  const float4 v = *(const float4*)(x + row * 256 + lane * 4);
  float s  = v.x + v.y + v.z + v.w;
  float s2 = v.x*v.x + v.y*v.y + v.z*v.z + v.w*v.w;
#pragma unroll
  for (int off = 32; off; off >>= 1){
    s  += __shfl_xor(s,  off);
    s2 += __shfl_xor(s2, off);
  }
  float mu  = s * (1.f/256.f);
  float var = s2 * (1.f/256.f) - mu * mu;
  float rs  = rsqrtf(var + 1e-5f);
  const float4 gv = *(const float4*)(g + lane * 4);
  const float4 bv = *(const float4*)(b + lane * 4);
  s16x4 o;
  o[0] = (short)f2bbits((v.x - mu) * rs * gv.x + bv.x);
  o[1] = (short)f2bbits((v.y - mu) * rs * gv.y + bv.y);
  o[2] = (short)f2bbits((v.z - mu) * rs * gv.z + bv.z);
  o[3] = (short)f2bbits((v.w - mu) * rs * gv.w + bv.w);
  *(s16x4*)(y + row * 256 + lane * 4) = o;
}

// ---------------- GEMM: C[M,N] = A[M,K] @ Bt[N,K]^T + bias, MFMA 128x128xBK64 ----------------
// EPI: 0 = bias+store bf16; 1 = bias+GELU+store bf16; 2 = proj: bias + window-reverse
// scatter + xfp += ; 3 = fc2: bias + xfp += val + addv (xfp IS d_out, fp32).
template<int EPI>
__global__ __launch_bounds__(256, 2) void k_gemm(
    const bfraw* __restrict__ A, const bfraw* __restrict__ Bt,
    const float* __restrict__ bias,
    bfraw* __restrict__ Cout, int ldc,
    float* __restrict__ xfp,
    const float* __restrict__ addv,
    int M, int N, int K, int shift)
{
  constexpr int BK = 64;
  __shared__ __align__(16) bfraw sA[128 * BK];
  __shared__ __align__(16) bfraw sB[128 * BK];
  const int tid = threadIdx.x, lane = tid & 63, w = tid >> 6;
  const int nbm = M >> 7;
  const int tm = blockIdx.x % nbm, tn = blockIdx.x / nbm;
  const int m0 = tm << 7, n0 = tn << 7;
  const int wm = w & 1, wn = w >> 1;
  f32x4 acc[4][4] = {};

  const int srow = (w << 5) + (lane >> 3);     // + i*8 per staging instr
  const int scol = (lane & 7) << 3;
  const bfraw* gA = A  + (size_t)(m0 + srow) * K + scol;
  const bfraw* gB = Bt + (size_t)(n0 + srow) * K + scol;

  for (int kt = 0; kt < K; kt += BK){
    __syncthreads();
#pragma unroll
    for (int i = 0; i < 4; ++i){
      GLOAD_LDS16(gA + (size_t)(i * 8) * K + kt, &sA[(w * 4 + i) * 512]);
      GLOAD_LDS16(gB + (size_t)(i * 8) * K + kt, &sB[(w * 4 + i) * 512]);
    }
    __syncthreads();
#pragma unroll
    for (int ks = 0; ks < 2; ++ks){
      const int ko = ks * 32 + ((lane >> 4) << 3);
      s16x8 af[4], bfr[4];
#pragma unroll
      for (int i = 0; i < 4; ++i){
        af[i]  = *(const s16x8*)&sA[((wm << 6) + (i << 4) + (lane & 15)) * BK + ko];
        bfr[i] = *(const s16x8*)&sB[((wn << 6) + (i << 4) + (lane & 15)) * BK + ko];
      }
#pragma unroll
      for (int mi = 0; mi < 4; ++mi)
#pragma unroll
        for (int ni = 0; ni < 4; ++ni)
          acc[mi][ni] = __builtin_amdgcn_mfma_f32_16x16x32_bf16(
              af[mi], bfr[ni], acc[mi][ni], 0, 0, 0);
    }
  }

  const int cl = lane & 15;
  float bv[4];
#pragma unroll
  for (int ni = 0; ni < 4; ++ni) bv[ni] = bias[n0 + (wn << 6) + (ni << 4) + cl];

#pragma unroll
  for (int mi = 0; mi < 4; ++mi){
#pragma unroll
    for (int j = 0; j < 4; ++j){
      const int r = m0 + (wm << 6) + (mi << 4) + ((lane >> 4) << 2) + j;
      size_t rowoff;
      if constexpr (EPI == 2){
        // windowed row r = b*4096 + wi*64 + n  ->  global row after reverse+roll
        int b_ = r >> 12, rem = r & 4095;
        int wi = rem >> 6, n_ = rem & 63;
        int gi = ((wi >> 3) * 8 + (n_ >> 3) + shift) & 63;
        int gj = ((wi & 7) * 8 + (n_ & 7) + shift) & 63;
        rowoff = ((size_t)b_ << 12) + gi * 64 + gj;
      } else {
        rowoff = (size_t)r;
      }
#pragma unroll
      for (int ni = 0; ni < 4; ++ni){
        float val = acc[mi][ni][j] + bv[ni];
        const int c = n0 + (wn << 6) + (ni << 4) + cl;
        if constexpr (EPI == 0){
          Cout[(size_t)r * ldc + c] = f2bbits(val);
        } else if constexpr (EPI == 1){
          val = 0.5f * val * (1.0f + erff(val * 0.70710678118654752f));
          Cout[(size_t)r * ldc + c] = f2bbits(val);
        } else if constexpr (EPI == 2){
          xfp[rowoff * 256 + c] += val;
        } else {
          size_t o = rowoff * 256 + c;
          xfp[o] = xfp[o] + val + addv[(size_t)(r >> 12) * 256 + c];
        }
      }
    }
  }
}

// ---------------- window attention: 1 wave per (window, head), flash-style ----------------
// K/V reg-staged into LDS (lgkmcnt-tracked ds_write: safe under 1-wave barrier elision).
__global__ __launch_bounds__(64) void k_attn(
    const bfraw* __restrict__ qkv, const float* __restrict__ rpb,
    bfraw* __restrict__ aout, int shift)
{
  __shared__ __align__(16) bfraw sK[64 * 32];
  __shared__ __align__(16) bfraw sV[64 * 32];
  __shared__ float sRpb[225];
  const int win = blockIdx.x >> 3, h = blockIdx.x & 7;
  const int b = win >> 6, wr = (win >> 3) & 7, wc = win & 7;
  const int lane = threadIdx.x;
  const int tr = lane >> 3, tc = lane & 7;

  // reg-stage K,V tiles [64][32]
  s16x8 kreg[4], vreg[4];
#pragma unroll
  for (int i = 0; i < 4; ++i){
    int row = i * 16 + (lane >> 2);
    int gi = (wr * 8 + (row >> 3) + shift) & 63;
    int gj = (wc * 8 + (row & 7) + shift) & 63;
    size_t grow = ((size_t)b << 12) + gi * 64 + gj;
    const bfraw* src = qkv + grow * 768 + 256 + h * 32 + (lane & 3) * 8;
    kreg[i] = *(const s16x8*)src;
    vreg[i] = *(const s16x8*)(src + 256);
  }
#pragma unroll
  for (int i = 0; i < 4; ++i){
    *(s16x8*)&sK[i * 512 + lane * 8] = kreg[i];
    *(s16x8*)&sV[i * 512 + lane * 8] = vreg[i];
  }
  for (int t = lane; t < 225; t += 64) sRpb[t] = rpb[t * 8 + h];

  // q row for this lane's query token (pre-scaled)
  const int qgi = (wr * 8 + tr + shift) & 63;
  const int qgj = (wc * 8 + tc + shift) & 63;
  const size_t qrow = ((size_t)b << 12) + qgi * 64 + qgj;
  const s16x8* qp = (const s16x8*)(qkv + qrow * 768 + h * 32);
  float q[32];
#pragma unroll
  for (int u = 0; u < 4; ++u){
    s16x8 t = qp[u];
#pragma unroll
    for (int e = 0; e < 8; ++e) q[u * 8 + e] = b2f(t[e]) * 0.17677669529663689f;
  }
  int qlab = 0;
  if (shift > 0){
    int gr = wr * 8 + tr, gc = wc * 8 + tc;
    int rh = gr < 56 ? 0 : (gr < 60 ? 1 : 2);
    int rw = gc < 56 ? 0 : (gc < 60 ? 1 : 2);
    qlab = rh * 3 + rw;
  }
  asm volatile("s_waitcnt vmcnt(0) lgkmcnt(0)" ::: "memory");
  __builtin_amdgcn_sched_barrier(0);
  __syncthreads();

  float mrun = -1e30f, lrun = 0.f, acc[32];
#pragma unroll
  for (int e = 0; e < 32; ++e) acc[e] = 0.f;

  for (int m = 0; m < 64; ++m){
    const s16x8* kr = (const s16x8*)&sK[m * 32];
    float s = 0.f;
#pragma unroll
    for (int u = 0; u < 4; ++u){
      s16x8 kv = kr[u];
#pragma unroll
      for (int e = 0; e < 8; ++e) s = fmaf(q[u * 8 + e], b2f(kv[e]), s);
    }
    const int mr = m >> 3, mc = m & 7;
    s += sRpb[(tr - mr + 7) * 15 + (tc - mc + 7)];
    if (shift > 0){
      int gr = wr * 8 + mr, gc = wc * 8 + mc;
      int rh = gr < 56 ? 0 : (gr < 60 ? 1 : 2);
      int rw = gc < 56 ? 0 : (gc < 60 ? 1 : 2);
      if (rh * 3 + rw != qlab) s -= 100.f;
    }
    float mn = fmaxf(mrun, s);
    float sc = __expf(mrun - mn);
    float p  = __expf(s - mn);
    mrun = mn;
    lrun = lrun * sc + p;
    const s16x8* vr = (const s16x8*)&sV[m * 32];
#pragma unroll
    for (int u = 0; u < 4; ++u){
      s16x8 vv = vr[u];
#pragma unroll
      for (int e = 0; e < 8; ++e) acc[u * 8 + e] = acc[u * 8 + e] * sc + p * b2f(vv[e]);
    }
  }
  const float inv = 1.f / lrun;
  bfraw* op = aout + ((size_t)win * 64 + lane) * 256 + h * 32;
#pragma unroll
  for (int u = 0; u < 4; ++u){
    s16x8 pack;
#pragma unroll
    for (int e = 0; e < 8; ++e) pack[e] = (short)f2bbits(acc[u * 8 + e] * inv);
    *(s16x8*)(op + u * 8) = pack;
  }
}

// ---------------- cross-attn collapsed: addv[d][b][j] (Tk==1 => softmax==1, o==v) ----------------
__global__ __launch_bounds__(256) void k_addvec(
    const float* __restrict__ emb, const float* __restrict__ qw, const float* __restrict__ qb,
    const float* __restrict__ inw, const float* __restrict__ inb,
    const float* __restrict__ outw, const float* __restrict__ outb,
    float* __restrict__ addv)
{
  const int d = blockIdx.x >> 4, b = blockIdx.x & 15;
  const int j = threadIdx.x;
  __shared__ float sc[256], sv[256];
  float a = qb[j];
  for (int k = 0; k < 512; ++k) a = fmaf(emb[b * 512 + k], qw[k * 256 + j], a);
  sc[j] = a; __syncthreads();
  float v = inb[d * 768 + 512 + j];
  const float* wrp = inw + (size_t)d * 768 * 256 + (size_t)(512 + j) * 256;
  for (int k = 0; k < 256; ++k) v = fmaf(sc[k], wrp[k], v);
  sv[j] = v; __syncthreads();
  float o = outb[d * 256 + j];
  const float* wop = outw + (size_t)d * 65536 + (size_t)j * 256;
  for (int k = 0; k < 256; ++k) o = fmaf(sv[k], wop[k], o);
  addv[(size_t)(d * 16 + b) * 256 + j] = o;
}

extern "C" void kernel_launch(void* const* d_in, const int* in_sizes, int n_in,
                              void* d_out, int out_size, void* d_ws, size_t ws_size,
                              hipStream_t stream)
{
  (void)in_sizes; (void)n_in; (void)out_size; (void)ws_size;
  const float* x_in     = (const float*)d_in[0];
  const float* emb      = (const float*)d_in[1];
  const float* qenc_w   = (const float*)d_in[2];
  const float* qenc_b   = (const float*)d_in[3];
  const float* n1_g     = (const float*)d_in[4];
  const float* n1_b     = (const float*)d_in[5];
  const float* qkv_w    = (const float*)d_in[6];
  const float* qkv_b    = (const float*)d_in[7];
  const float* rpb      = (const float*)d_in[8];
  const float* proj_w   = (const float*)d_in[9];
  const float* proj_b   = (const float*)d_in[10];
  const float* n2_g     = (const float*)d_in[11];
  const float* n2_b     = (const float*)d_in[12];
  const float* fc1_w    = (const float*)d_in[13];
  const float* fc1_b    = (const float*)d_in[14];
  const float* fc2_w    = (const float*)d_in[15];
  const float* fc2_b    = (const float*)d_in[16];
  const float* ca_in_w  = (const float*)d_in[19];
  const float* ca_in_b  = (const float*)d_in[20];
  const float* ca_out_w = (const float*)d_in[21];
  const float* ca_out_b = (const float*)d_in[22];

  float* xfp  = (float*)d_out;                           // fp32 residual == output
  char* ws = (char*)d_ws;
  bfraw* ybuf = (bfraw*)ws;                              // 32MB bf16 (LN out / attn out)
  bfraw* qkvb = (bfraw*)(ws + ((size_t)32 << 20));       // 128MB (qkv 96MB, then h1 128MB)
  bfraw* wT   = (bfraw*)(ws + ((size_t)160 << 20));

  bfraw *qkvT[2], *projT[2], *fc1T[2], *fc2T[2];
  size_t off = 0;
  for (int d = 0; d < 2; ++d){ qkvT[d] = wT + off; off += 768 * 256; }
  for (int d = 0; d < 2; ++d){ projT[d] = wT + off; off += 256 * 256; }
  for (int d = 0; d < 2; ++d){ fc1T[d] = wT + off; off += 1024 * 256; }
  for (int d = 0; d < 2; ++d){ fc2T[d] = wT + off; off += 256 * 1024; }
  float* addv = (float*)(wT + ((off + 1) & ~(size_t)1)); // [2][16][256] fp32

  for (int d = 0; d < 2; ++d){
    k_tr<<<(256 * 768  + 255) / 256, 256, 0, stream>>>(qkv_w  + (size_t)d * 256 * 768,  qkvT[d], 256, 768);
    k_tr<<<(256 * 256  + 255) / 256, 256, 0, stream>>>(proj_w + (size_t)d * 256 * 256,  projT[d], 256, 256);
    k_tr<<<(256 * 1024 + 255) / 256, 256, 0, stream>>>(fc1_w  + (size_t)d * 256 * 1024, fc1T[d], 256, 1024);
    k_tr<<<(1024 * 256 + 255) / 256, 256, 0, stream>>>(fc2_w  + (size_t)d * 1024 * 256, fc2T[d], 1024, 256);
  }
  k_addvec<<<32, 256, 0, stream>>>(emb, qenc_w, qenc_b, ca_in_w, ca_in_b, ca_out_w, ca_out_b, addv);
  k_copy<<<16384, 256, 0, stream>>>(x_in, xfp);

  for (int d = 0; d < 2; ++d){
    const int shift = d ? 4 : 0;
    k_ln<<<16384, 256, 0, stream>>>(xfp, n1_g + d * 256, n1_b + d * 256, ybuf);
    k_gemm<0><<<512 * 6, 256, 0, stream>>>(ybuf, qkvT[d], qkv_b + d * 768, qkvb, 768,
                                           nullptr, nullptr, 65536, 768, 256, 0);
    k_attn<<<8192, 64, 0, stream>>>(qkvb, rpb + (size_t)d * 225 * 8, ybuf, shift);
    k_gemm<2><<<512 * 2, 256, 0, stream>>>(ybuf, projT[d], proj_b + d * 256, nullptr, 0,
                                           xfp, nullptr, 65536, 256, 256, shift);
    k_ln<<<16384, 256, 0, stream>>>(xfp, n2_g + d * 256, n2_b + d * 256, ybuf);
    k_gemm<1><<<512 * 8, 256, 0, stream>>>(ybuf, fc1T[d], fc1_b + d * 1024, qkvb, 1024,
                                           nullptr, nullptr, 65536, 1024, 256, 0);
    k_gemm<3><<<512 * 2, 256, 0, stream>>>(qkvb, fc2T[d], fc2_b + d * 256, nullptr, 0,
                                           xfp, addv + (size_t)d * 16 * 256,
                                           65536, 256, 1024, 0);
  }
}

// Round 5
// 763.867 us; speedup vs baseline: 1.2383x; 1.2383x over previous
//
#include <hip/hip_runtime.h>

// SwinJSCC encoder, 2 depths. I/O fp32; internal GEMM operands bf16; fp32 residual
// stream lives IN d_out. ws map: [0,32M) ybuf bf16 | [32M,160M) qkv bf16 (96MB used)
// then reused as h1 (128MB) | [160M,166M) wT (bf16 transposed weights) + addv fp32 |
// [166M,167M) biasPk fp32 (attn bias+mask in MFMA C-register layout).

typedef unsigned short bfraw;
typedef short s16x8 __attribute__((ext_vector_type(8)));
typedef short s16x4 __attribute__((ext_vector_type(4)));
typedef float f32x4 __attribute__((ext_vector_type(4)));

#define DEV static __device__ __forceinline__

DEV float b2f(int u){
  union { unsigned int i; float f; } x;
  x.i = ((unsigned int)u & 0xffffu) << 16;
  return x.f;
}
DEV unsigned short f2bbits(float f){
  union { float f; unsigned int i; } x; x.f = f;
  unsigned int i = x.i;
  unsigned int lsb = (i >> 16) & 1u;
  i += 0x7fffu + lsb;                 // round-to-nearest-even
  return (unsigned short)(i >> 16);
}

#define GLOAD_LDS16(g, l) __builtin_amdgcn_global_load_lds(                      \
    (const __attribute__((address_space(1))) void*)(g),                          \
    (__attribute__((address_space(3))) void*)(l), 16, 0, 0)

// ---------------- fp32 copy: x input -> residual stream (d_out) ----------------
__global__ void k_copy(const float* __restrict__ xin, float* __restrict__ xfp){
  size_t i = ((size_t)blockIdx.x * 256 + threadIdx.x) * 4;
  *(float4*)(xfp + i) = *(const float4*)(xin + i);
}

// ---------------- weight transpose+cast [K,N] fp32 -> [N,K] bf16 ----------------
__global__ void k_tr(const float* __restrict__ in, bfraw* __restrict__ out, int K, int N){
  int idx = blockIdx.x * 256 + threadIdx.x;
  if (idx >= K * N) return;
  int n = idx / K, k = idx - n * K;
  out[idx] = f2bbits(in[(size_t)k * N + n]);
}

// ---------------- LayerNorm over C=256 (fp32 in, bf16 out), one wave per row ----------------
__global__ __launch_bounds__(256) void k_ln(
    const float* __restrict__ x, const float* __restrict__ g,
    const float* __restrict__ b, bfraw* __restrict__ y)
{
  const int lane = threadIdx.x & 63, wv = threadIdx.x >> 6;
  const size_t row = (size_t)blockIdx.x * 4 + wv;
  const float4 v = *(const float4*)(x + row * 256 + lane * 4);
  float s  = v.x + v.y + v.z + v.w;
  float s2 = v.x*v.x + v.y*v.y + v.z*v.z + v.w*v.w;
#pragma unroll
  for (int off = 32; off; off >>= 1){
    s  += __shfl_xor(s,  off);
    s2 += __shfl_xor(s2, off);
  }
  float mu  = s * (1.f/256.f);
  float var = s2 * (1.f/256.f) - mu * mu;
  float rs  = rsqrtf(var + 1e-5f);
  const float4 gv = *(const float4*)(g + lane * 4);
  const float4 bv = *(const float4*)(b + lane * 4);
  s16x4 o;
  o[0] = (short)f2bbits((v.x - mu) * rs * gv.x + bv.x);
  o[1] = (short)f2bbits((v.y - mu) * rs * gv.y + bv.y);
  o[2] = (short)f2bbits((v.z - mu) * rs * gv.z + bv.z);
  o[3] = (short)f2bbits((v.w - mu) * rs * gv.w + bv.w);
  *(s16x4*)(y + row * 256 + lane * 4) = o;
}

// ---------------- GEMM: C[M,N] = A[M,K] @ Bt[N,K]^T + bias, MFMA 128x128xBK64 ----------------
template<int EPI>
__global__ __launch_bounds__(256, 2) void k_gemm(
    const bfraw* __restrict__ A, const bfraw* __restrict__ Bt,
    const float* __restrict__ bias,
    bfraw* __restrict__ Cout, int ldc,
    float* __restrict__ xfp,
    const float* __restrict__ addv,
    int M, int N, int K, int shift)
{
  constexpr int BK = 64;
  __shared__ __align__(16) bfraw sA[128 * BK];
  __shared__ __align__(16) bfraw sB[128 * BK];
  const int tid = threadIdx.x, lane = tid & 63, w = tid >> 6;
  const int nbm = M >> 7;
  const int tm = blockIdx.x % nbm, tn = blockIdx.x / nbm;
  const int m0 = tm << 7, n0 = tn << 7;
  const int wm = w & 1, wn = w >> 1;
  f32x4 acc[4][4] = {};

  const int srow = (w << 5) + (lane >> 3);
  const int scol = (lane & 7) << 3;
  const bfraw* gA = A  + (size_t)(m0 + srow) * K + scol;
  const bfraw* gB = Bt + (size_t)(n0 + srow) * K + scol;

  for (int kt = 0; kt < K; kt += BK){
    __syncthreads();
#pragma unroll
    for (int i = 0; i < 4; ++i){
      GLOAD_LDS16(gA + (size_t)(i * 8) * K + kt, &sA[(w * 4 + i) * 512]);
      GLOAD_LDS16(gB + (size_t)(i * 8) * K + kt, &sB[(w * 4 + i) * 512]);
    }
    __syncthreads();
#pragma unroll
    for (int ks = 0; ks < 2; ++ks){
      const int ko = ks * 32 + ((lane >> 4) << 3);
      s16x8 af[4], bfr[4];
#pragma unroll
      for (int i = 0; i < 4; ++i){
        af[i]  = *(const s16x8*)&sA[((wm << 6) + (i << 4) + (lane & 15)) * BK + ko];
        bfr[i] = *(const s16x8*)&sB[((wn << 6) + (i << 4) + (lane & 15)) * BK + ko];
      }
#pragma unroll
      for (int mi = 0; mi < 4; ++mi)
#pragma unroll
        for (int ni = 0; ni < 4; ++ni)
          acc[mi][ni] = __builtin_amdgcn_mfma_f32_16x16x32_bf16(
              af[mi], bfr[ni], acc[mi][ni], 0, 0, 0);
    }
  }

  const int cl = lane & 15;
  float bv[4];
#pragma unroll
  for (int ni = 0; ni < 4; ++ni) bv[ni] = bias[n0 + (wn << 6) + (ni << 4) + cl];

#pragma unroll
  for (int mi = 0; mi < 4; ++mi){
#pragma unroll
    for (int j = 0; j < 4; ++j){
      const int r = m0 + (wm << 6) + (mi << 4) + ((lane >> 4) << 2) + j;
      size_t rowoff;
      if constexpr (EPI == 2){
        int b_ = r >> 12, rem = r & 4095;
        int wi = rem >> 6, n_ = rem & 63;
        int gi = ((wi >> 3) * 8 + (n_ >> 3) + shift) & 63;
        int gj = ((wi & 7) * 8 + (n_ & 7) + shift) & 63;
        rowoff = ((size_t)b_ << 12) + gi * 64 + gj;
      } else {
        rowoff = (size_t)r;
      }
#pragma unroll
      for (int ni = 0; ni < 4; ++ni){
        float val = acc[mi][ni][j] + bv[ni];
        const int c = n0 + (wn << 6) + (ni << 4) + cl;
        if constexpr (EPI == 0){
          Cout[(size_t)r * ldc + c] = f2bbits(val);
        } else if constexpr (EPI == 1){
          val = 0.5f * val * (1.0f + erff(val * 0.70710678118654752f));
          Cout[(size_t)r * ldc + c] = f2bbits(val);
        } else if constexpr (EPI == 2){
          xfp[rowoff * 256 + c] += val;
        } else {
          size_t o = rowoff * 256 + c;
          xfp[o] = xfp[o] + val + addv[(size_t)(r >> 12) * 256 + c];
        }
      }
    }
  }
}

// ---------------- attn bias+mask precompute, in MFMA C-register layout ----------------
// biasPk[d][cls][h][mi*4+ni][lane][j] : value for S^T tile (mi,ni), lane, reg j.
// S^T(k,q): k = 16mi + 4*(lane>>4) + j, q = 16ni + (lane&15).
__global__ __launch_bounds__(64) void k_bias(const float* __restrict__ rpb,
                                             float* __restrict__ biasPk)
{
  const int blk = blockIdx.x;
  const int d = blk >> 5, cls = (blk >> 3) & 3, h = blk & 7;
  const int l = threadIdx.x, lo16 = l & 15, hg = l >> 4;
  const float* rp = rpb + (size_t)d * 225 * 8;
  float* ob = biasPk + (((size_t)d * 4 + cls) * 8 + h) * 4096;
#pragma unroll
  for (int mi = 0; mi < 4; ++mi)
#pragma unroll
    for (int ni = 0; ni < 4; ++ni)
#pragma unroll
      for (int j = 0; j < 4; ++j){
        int k = 16 * mi + 4 * hg + j, q = 16 * ni + lo16;
        int qr = q >> 3, qc = q & 7, kr = k >> 3, kc = k & 7;
        float v = rp[((qr - kr + 7) * 15 + (qc - kc + 7)) * 8 + h];
        if (d == 1){
          int lq = ((cls >> 1) ? (qr < 4 ? 1 : 2) : 0) * 3 + ((cls & 1) ? (qc < 4 ? 1 : 2) : 0);
          int lk = ((cls >> 1) ? (kr < 4 ? 1 : 2) : 0) * 3 + ((cls & 1) ? (kc < 4 ? 1 : 2) : 0);
          if (lq != lk) v -= 100.f;
        }
        ob[(mi * 4 + ni) * 256 + l * 4 + j] = v;
      }
}

// ---------------- window attention via MFMA: 1 wave per (window, head) ----------------
// S^T = K @ Q^T (both fragments direct from global, no transpose needed);
// exact softmax over k (in-lane + shfl); P -> bf16 via cvt_pk, LDS round-trip
// ([q][k], XOR-swizzled) to A-fragment layout; O = P @ V with V B-frags from LDS.
__global__ __launch_bounds__(64) void k_attn(
    const bfraw* __restrict__ qkv, const float* __restrict__ biasPk,
    bfraw* __restrict__ aout, int shift)
{
  __shared__ __align__(16) bfraw sV[64 * 32];   // [k][d]  4KB
  __shared__ __align__(16) bfraw sP[64 * 64];   // [q][k]  8KB, swizzled
  const int win = blockIdx.x >> 3, h = blockIdx.x & 7;
  const int b = win >> 6, wr = (win >> 3) & 7, wc = win & 7;
  const int l = threadIdx.x, lo16 = l & 15, hg = l >> 4;

  // token n (window index) -> global row after roll
  auto grow_of = [&](int n) -> size_t {
    int gi = (wr * 8 + (n >> 3) + shift) & 63;
    int gj = (wc * 8 + (n & 7) + shift) & 63;
    return ((size_t)b << 12) + gi * 64 + gj;
  };

  // stage V [64][32] into LDS
  s16x8 vreg[4];
#pragma unroll
  for (int i = 0; i < 4; ++i){
    int row = i * 16 + (l >> 2);
    vreg[i] = *(const s16x8*)(qkv + grow_of(row) * 768 + 512 + h * 32 + (l & 3) * 8);
  }
#pragma unroll
  for (int i = 0; i < 4; ++i)
    *(s16x8*)&sV[i * 512 + l * 8] = vreg[i];

  // K (A-frag) and Q (B-frag) direct from global: lane row = 16t + lo16, d = hg*8..+7
  s16x8 aK[4], bQ[4];
#pragma unroll
  for (int t = 0; t < 4; ++t){
    const bfraw* base = qkv + grow_of(16 * t + lo16) * 768 + h * 32 + hg * 8;
    bQ[t] = *(const s16x8*)base;          // Q plane
    aK[t] = *(const s16x8*)(base + 256);  // K plane
  }

  // S^T[k][q]: acc[mi][ni], k-tiles mi, q-tiles ni
  f32x4 acc[4][4] = {};
#pragma unroll
  for (int mi = 0; mi < 4; ++mi)
#pragma unroll
    for (int ni = 0; ni < 4; ++ni)
      acc[mi][ni] = __builtin_amdgcn_mfma_f32_16x16x32_bf16(aK[mi], bQ[ni], acc[mi][ni], 0, 0, 0);

  // scale + bias(+mask), precomputed in this exact register layout
  const int cls = ((wr == 7) ? 2 : 0) | ((wc == 7) ? 1 : 0);
  const float* bb = biasPk + ((size_t)(cls * 8 + h)) * 4096;
#pragma unroll
  for (int mi = 0; mi < 4; ++mi)
#pragma unroll
    for (int ni = 0; ni < 4; ++ni){
      f32x4 bv4 = *(const f32x4*)(bb + (mi * 4 + ni) * 256 + l * 4);
      acc[mi][ni] = acc[mi][ni] * 0.17677669529663689f + bv4;
    }

  // exact softmax over k (rows of S^T) for each of the lane's 4 q-columns
#pragma unroll
  for (int ni = 0; ni < 4; ++ni){
    float m = acc[0][ni][0];
#pragma unroll
    for (int mi = 0; mi < 4; ++mi)
#pragma unroll
      for (int j = 0; j < 4; ++j) m = fmaxf(m, acc[mi][ni][j]);
    m = fmaxf(m, __shfl_xor(m, 16));
    m = fmaxf(m, __shfl_xor(m, 32));
    float s = 0.f;
#pragma unroll
    for (int mi = 0; mi < 4; ++mi)
#pragma unroll
      for (int j = 0; j < 4; ++j){
        float e = __expf(acc[mi][ni][j] - m);
        acc[mi][ni][j] = e; s += e;
      }
    s += __shfl_xor(s, 16);
    s += __shfl_xor(s, 32);
    float inv = 1.f / s;
#pragma unroll
    for (int mi = 0; mi < 4; ++mi)
#pragma unroll
      for (int j = 0; j < 4; ++j) acc[mi][ni][j] *= inv;
  }

  // pack P to bf16 and write [q][k] (XOR-swizzled) to LDS
#pragma unroll
  for (int mi = 0; mi < 4; ++mi)
#pragma unroll
    for (int ni = 0; ni < 4; ++ni){
      unsigned int w0, w1;
      asm("v_cvt_pk_bf16_f32 %0, %1, %2" : "=v"(w0) : "v"(acc[mi][ni][0]), "v"(acc[mi][ni][1]));
      asm("v_cvt_pk_bf16_f32 %0, %1, %2" : "=v"(w1) : "v"(acc[mi][ni][2]), "v"(acc[mi][ni][3]));
      int q = 16 * ni + lo16;
      int ad = (q * 128 + (16 * mi + 4 * hg) * 2) ^ ((q & 7) << 4);
      *(uint2*)((char*)sP + ad) = make_uint2(w0, w1);
    }

  asm volatile("s_waitcnt lgkmcnt(0)" ::: "memory");
  __builtin_amdgcn_sched_barrier(0);

  // O[q][d] = P @ V : A-frags from sP, B-frags from sV
  f32x4 opv[4][2] = {};
#pragma unroll
  for (int kt = 0; kt < 2; ++kt){
    s16x8 ap[4];
#pragma unroll
    for (int qi = 0; qi < 4; ++qi){
      int q = 16 * qi + lo16;
      int ad = (q * 128 + (kt * 32 + hg * 8) * 2) ^ ((q & 7) << 4);
      ap[qi] = *(const s16x8*)((const char*)sP + ad);
    }
    s16x8 vb[2];
#pragma unroll
    for (int nt = 0; nt < 2; ++nt)
#pragma unroll
      for (int e = 0; e < 8; ++e)
        vb[nt][e] = (short)sV[(kt * 32 + hg * 8 + e) * 32 + nt * 16 + lo16];
#pragma unroll
    for (int qi = 0; qi < 4; ++qi)
#pragma unroll
      for (int nt = 0; nt < 2; ++nt)
        opv[qi][nt] = __builtin_amdgcn_mfma_f32_16x16x32_bf16(ap[qi], vb[nt], opv[qi][nt], 0, 0, 0);
  }

  // store O (C layout: row q = 16qi+4hg+j, col d = 16nt+lo16) to ybuf windowed rows
  bfraw* ob = aout + ((size_t)win * 64) * 256 + h * 32 + lo16;
#pragma unroll
  for (int qi = 0; qi < 4; ++qi)
#pragma unroll
    for (int nt = 0; nt < 2; ++nt)
#pragma unroll
      for (int j = 0; j < 4; ++j)
        ob[(size_t)(16 * qi + 4 * hg + j) * 256 + nt * 16] = f2bbits(opv[qi][nt][j]);
}

// ---------------- cross-attn collapsed: addv[d][b][j] (Tk==1 => softmax==1, o==v) ----------------
__global__ __launch_bounds__(256) void k_addvec(
    const float* __restrict__ emb, const float* __restrict__ qw, const float* __restrict__ qb,
    const float* __restrict__ inw, const float* __restrict__ inb,
    const float* __restrict__ outw, const float* __restrict__ outb,
    float* __restrict__ addv)
{
  const int d = blockIdx.x >> 4, b = blockIdx.x & 15;
  const int j = threadIdx.x;
  __shared__ float sc[256], sv[256];
  float a = qb[j];
  for (int k = 0; k < 512; ++k) a = fmaf(emb[b * 512 + k], qw[k * 256 + j], a);
  sc[j] = a; __syncthreads();
  float v = inb[d * 768 + 512 + j];
  const float* wrp = inw + (size_t)d * 768 * 256 + (size_t)(512 + j) * 256;
  for (int k = 0; k < 256; ++k) v = fmaf(sc[k], wrp[k], v);
  sv[j] = v; __syncthreads();
  float o = outb[d * 256 + j];
  const float* wop = outw + (size_t)d * 65536 + (size_t)j * 256;
  for (int k = 0; k < 256; ++k) o = fmaf(sv[k], wop[k], o);
  addv[(size_t)(d * 16 + b) * 256 + j] = o;
}

extern "C" void kernel_launch(void* const* d_in, const int* in_sizes, int n_in,
                              void* d_out, int out_size, void* d_ws, size_t ws_size,
                              hipStream_t stream)
{
  (void)in_sizes; (void)n_in; (void)out_size; (void)ws_size;
  const float* x_in     = (const float*)d_in[0];
  const float* emb      = (const float*)d_in[1];
  const float* qenc_w   = (const float*)d_in[2];
  const float* qenc_b   = (const float*)d_in[3];
  const float* n1_g     = (const float*)d_in[4];
  const float* n1_b     = (const float*)d_in[5];
  const float* qkv_w    = (const float*)d_in[6];
  const float* qkv_b    = (const float*)d_in[7];
  const float* rpb      = (const float*)d_in[8];
  const float* proj_w   = (const float*)d_in[9];
  const float* proj_b   = (const float*)d_in[10];
  const float* n2_g     = (const float*)d_in[11];
  const float* n2_b     = (const float*)d_in[12];
  const float* fc1_w    = (const float*)d_in[13];
  const float* fc1_b    = (const float*)d_in[14];
  const float* fc2_w    = (const float*)d_in[15];
  const float* fc2_b    = (const float*)d_in[16];
  const float* ca_in_w  = (const float*)d_in[19];
  const float* ca_in_b  = (const float*)d_in[20];
  const float* ca_out_w = (const float*)d_in[21];
  const float* ca_out_b = (const float*)d_in[22];

  float* xfp  = (float*)d_out;                           // fp32 residual == output
  char* ws = (char*)d_ws;
  bfraw* ybuf = (bfraw*)ws;                              // 32MB bf16
  bfraw* qkvb = (bfraw*)(ws + ((size_t)32 << 20));       // 128MB (qkv 96MB, then h1)
  bfraw* wT   = (bfraw*)(ws + ((size_t)160 << 20));
  float* biasPk = (float*)(ws + ((size_t)166 << 20));    // [2][4][8][4096] f32 = 1MB

  bfraw *qkvT[2], *projT[2], *fc1T[2], *fc2T[2];
  size_t off = 0;
  for (int d = 0; d < 2; ++d){ qkvT[d] = wT + off; off += 768 * 256; }
  for (int d = 0; d < 2; ++d){ projT[d] = wT + off; off += 256 * 256; }
  for (int d = 0; d < 2; ++d){ fc1T[d] = wT + off; off += 1024 * 256; }
  for (int d = 0; d < 2; ++d){ fc2T[d] = wT + off; off += 256 * 1024; }
  float* addv = (float*)(wT + ((off + 1) & ~(size_t)1)); // [2][16][256] fp32

  for (int d = 0; d < 2; ++d){
    k_tr<<<(256 * 768  + 255) / 256, 256, 0, stream>>>(qkv_w  + (size_t)d * 256 * 768,  qkvT[d], 256, 768);
    k_tr<<<(256 * 256  + 255) / 256, 256, 0, stream>>>(proj_w + (size_t)d * 256 * 256,  projT[d], 256, 256);
    k_tr<<<(256 * 1024 + 255) / 256, 256, 0, stream>>>(fc1_w  + (size_t)d * 256 * 1024, fc1T[d], 256, 1024);
    k_tr<<<(1024 * 256 + 255) / 256, 256, 0, stream>>>(fc2_w  + (size_t)d * 1024 * 256, fc2T[d], 1024, 256);
  }
  k_bias<<<64, 64, 0, stream>>>(rpb, biasPk);
  k_addvec<<<32, 256, 0, stream>>>(emb, qenc_w, qenc_b, ca_in_w, ca_in_b, ca_out_w, ca_out_b, addv);
  k_copy<<<16384, 256, 0, stream>>>(x_in, xfp);

  for (int d = 0; d < 2; ++d){
    const int shift = d ? 4 : 0;
    k_ln<<<16384, 256, 0, stream>>>(xfp, n1_g + d * 256, n1_b + d * 256, ybuf);
    k_gemm<0><<<512 * 6, 256, 0, stream>>>(ybuf, qkvT[d], qkv_b + d * 768, qkvb, 768,
                                           nullptr, nullptr, 65536, 768, 256, 0);
    k_attn<<<8192, 64, 0, stream>>>(qkvb, biasPk + (size_t)d * 4 * 8 * 4096, ybuf, shift);
    k_gemm<2><<<512 * 2, 256, 0, stream>>>(ybuf, projT[d], proj_b + d * 256, nullptr, 0,
                                           xfp, nullptr, 65536, 256, 256, shift);
    k_ln<<<16384, 256, 0, stream>>>(xfp, n2_g + d * 256, n2_b + d * 256, ybuf);
    k_gemm<1><<<512 * 8, 256, 0, stream>>>(ybuf, fc1T[d], fc1_b + d * 1024, qkvb, 1024,
                                           nullptr, nullptr, 65536, 1024, 256, 0);
    k_gemm<3><<<512 * 2, 256, 0, stream>>>(qkvb, fc2T[d], fc2_b + d * 256, nullptr, 0,
                                           xfp, addv + (size_t)d * 16 * 256,
                                           65536, 256, 1024, 0);
  }
}

// Round 6
// 686.150 us; speedup vs baseline: 1.3786x; 1.1133x over previous
//
#include <hip/hip_runtime.h>

// SwinJSCC encoder, 2 depths. I/O fp32; internal GEMM operands bf16; fp32 residual
// stream lives IN d_out. ws map: [0,32M) ybuf bf16 | [32M,160M) qkv bf16 (96MB used)
// then reused as h1 (128MB) | [160M,166M) wT (bf16 transposed weights) + addv fp32 |
// [166M,167M) biasPk fp32 (attn bias+mask in MFMA C-register layout).

typedef unsigned short bfraw;
typedef short s16x8 __attribute__((ext_vector_type(8)));
typedef short s16x4 __attribute__((ext_vector_type(4)));
typedef float f32x4 __attribute__((ext_vector_type(4)));

#define DEV static __device__ __forceinline__

DEV float b2f(int u){
  union { unsigned int i; float f; } x;
  x.i = ((unsigned int)u & 0xffffu) << 16;
  return x.f;
}
DEV unsigned short f2bbits(float f){
  union { float f; unsigned int i; } x; x.f = f;
  unsigned int i = x.i;
  unsigned int lsb = (i >> 16) & 1u;
  i += 0x7fffu + lsb;                 // round-to-nearest-even
  return (unsigned short)(i >> 16);
}
DEV float gelu_tanh(float x){
  // 0.5x(1+tanh(0.79788456(x+0.044715x^3))) == x*sigmoid(2t); |err vs erf| < 3e-3
  float t2 = 1.5957691216057308f * fmaf(0.044715f * x * x, x, x);
  float e = __expf(-t2);
  return x * __builtin_amdgcn_rcpf(1.f + e);
}

#define GLOAD_LDS16(g, l) __builtin_amdgcn_global_load_lds(                      \
    (const __attribute__((address_space(1))) void*)(g),                          \
    (__attribute__((address_space(3))) void*)(l), 16, 0, 0)

// ---------------- weight transpose+cast [K,N] fp32 -> [N,K] bf16 ----------------
__global__ void k_tr(const float* __restrict__ in, bfraw* __restrict__ out, int K, int N){
  int idx = blockIdx.x * 256 + threadIdx.x;
  if (idx >= K * N) return;
  int n = idx / K, k = idx - n * K;
  out[idx] = f2bbits(in[(size_t)k * N + n]);
}

// ---------------- LayerNorm over C=256 (fp32 in, bf16 out), one wave per row ----------------
__global__ __launch_bounds__(256) void k_ln(
    const float* __restrict__ x, const float* __restrict__ g,
    const float* __restrict__ b, bfraw* __restrict__ y)
{
  const int lane = threadIdx.x & 63, wv = threadIdx.x >> 6;
  const size_t row = (size_t)blockIdx.x * 4 + wv;
  const float4 v = *(const float4*)(x + row * 256 + lane * 4);
  float s  = v.x + v.y + v.z + v.w;
  float s2 = v.x*v.x + v.y*v.y + v.z*v.z + v.w*v.w;
#pragma unroll
  for (int off = 32; off; off >>= 1){
    s  += __shfl_xor(s,  off);
    s2 += __shfl_xor(s2, off);
  }
  float mu  = s * (1.f/256.f);
  float var = s2 * (1.f/256.f) - mu * mu;
  float rs  = rsqrtf(var + 1e-5f);
  const float4 gv = *(const float4*)(g + lane * 4);
  const float4 bv = *(const float4*)(b + lane * 4);
  s16x4 o;
  o[0] = (short)f2bbits((v.x - mu) * rs * gv.x + bv.x);
  o[1] = (short)f2bbits((v.y - mu) * rs * gv.y + bv.y);
  o[2] = (short)f2bbits((v.z - mu) * rs * gv.z + bv.z);
  o[3] = (short)f2bbits((v.w - mu) * rs * gv.w + bv.w);
  *(s16x4*)(y + row * 256 + lane * 4) = o;
}

// ---------------- GEMM: C[M,N] = A[M,K] @ Bt[N,K]^T + bias, MFMA 128x128xBK64 ----------------
// Computes C^T fragments (mfma(B,A)) so each lane holds 4 CONSECUTIVE COLUMNS ->
// vectorized epilogue. LDS XOR-swizzled (linear gload_lds dest + pre-swizzled
// global source + swizzled read). XCD-chunked block remap, tn-fastest for A reuse.
// EPI: 0 bias+store bf16; 1 bias+GELU(tanh)+store bf16; 2 proj: bias+window-reverse
// scatter, xfp = xin + val; 3 fc2: xfp += val + addv.
template<int EPI>
__global__ __launch_bounds__(256, 2) void k_gemm(
    const bfraw* __restrict__ A, const bfraw* __restrict__ Bt,
    const float* __restrict__ bias,
    bfraw* __restrict__ Cout, int ldc,
    float* __restrict__ xfp, const float* __restrict__ xin,
    const float* __restrict__ addv,
    int M, int N, int K, int shift)
{
  constexpr int BK = 64;
  __shared__ __align__(16) bfraw sA[128 * BK];
  __shared__ __align__(16) bfraw sB[128 * BK];
  const int tid = threadIdx.x, lane = tid & 63, w = tid >> 6;
  const int lo16 = lane & 15, hg = lane >> 4;
  const int nbm = M >> 7, nbn = N >> 7;
  const int nwg = nbm * nbn;
  const int bid = blockIdx.x;
  const int wgid = (bid & 7) * (nwg >> 3) + (bid >> 3);
  const int tn = wgid % nbn, tm = wgid / nbn;
  const int m0 = tm << 7, n0 = tn << 7;
  const int wm = w & 1, wn = w >> 1;
  f32x4 acc[4][4] = {};                       // [ni][mi] : C^T tiles

  const int srow = (w << 5) + (lane >> 3);
  const int scol = (((lane & 7) ^ (lane >> 3)) << 3);  // inverse-swizzled source col
  const int ksw  = (lane & 7) << 3;                    // read-side XOR (row&7)<<3
  const bfraw* gA = A  + (size_t)(m0 + srow) * K + scol;
  const bfraw* gB = Bt + (size_t)(n0 + srow) * K + scol;

  for (int kt = 0; kt < K; kt += BK){
    __syncthreads();
#pragma unroll
    for (int i = 0; i < 4; ++i){
      GLOAD_LDS16(gA + (size_t)(i * 8) * K + kt, &sA[(w * 4 + i) * 512]);
      GLOAD_LDS16(gB + (size_t)(i * 8) * K + kt, &sB[(w * 4 + i) * 512]);
    }
    __syncthreads();
#pragma unroll
    for (int ks = 0; ks < 2; ++ks){
      const int ko = (ks * 32 + (hg << 3)) ^ ksw;
      s16x8 af[4], bfr[4];
#pragma unroll
      for (int i = 0; i < 4; ++i){
        af[i]  = *(const s16x8*)&sA[((wm << 6) + (i << 4) + lo16) * BK + ko];
        bfr[i] = *(const s16x8*)&sB[((wn << 6) + (i << 4) + lo16) * BK + ko];
      }
#pragma unroll
      for (int ni = 0; ni < 4; ++ni)
#pragma unroll
        for (int mi = 0; mi < 4; ++mi)
          acc[ni][mi] = __builtin_amdgcn_mfma_f32_16x16x32_bf16(
              bfr[ni], af[mi], acc[ni][mi], 0, 0, 0);
    }
  }

  const int cb = n0 + (wn << 6) + 4 * hg;     // column base; lane's cols cb+ni*16+j
  f32x4 bv4[4];
#pragma unroll
  for (int ni = 0; ni < 4; ++ni) bv4[ni] = *(const f32x4*)(bias + cb + ni * 16);

#pragma unroll
  for (int mi = 0; mi < 4; ++mi){
    const int r = m0 + (wm << 6) + (mi << 4) + lo16;
    if constexpr (EPI == 0 || EPI == 1){
      bfraw* crow = Cout + (size_t)r * ldc + cb;
#pragma unroll
      for (int ni = 0; ni < 4; ++ni){
        f32x4 v = acc[ni][mi] + bv4[ni];
        s16x4 o;
#pragma unroll
        for (int j = 0; j < 4; ++j){
          float val = v[j];
          if constexpr (EPI == 1) val = gelu_tanh(val);
          o[j] = (short)f2bbits(val);
        }
        *(s16x4*)(crow + ni * 16) = o;
      }
    } else if constexpr (EPI == 2){
      int b_ = r >> 12, rem = r & 4095;
      int wi = rem >> 6, n_ = rem & 63;
      int gi = ((wi >> 3) * 8 + (n_ >> 3) + shift) & 63;
      int gj = ((wi & 7) * 8 + (n_ & 7) + shift) & 63;
      size_t rowoff = ((size_t)b_ << 12) + gi * 64 + gj;
      const float* xi = xin + rowoff * 256 + cb;
      float*       xo = xfp + rowoff * 256 + cb;
#pragma unroll
      for (int ni = 0; ni < 4; ++ni){
        f32x4 v = acc[ni][mi] + bv4[ni] + *(const f32x4*)(xi + ni * 16);
        *(f32x4*)(xo + ni * 16) = v;
      }
    } else {
      const float* av = addv + (size_t)(r >> 12) * 256 + cb;
      float* xo = xfp + (size_t)r * 256 + cb;
#pragma unroll
      for (int ni = 0; ni < 4; ++ni){
        f32x4 v = acc[ni][mi] + bv4[ni] + *(const f32x4*)(xo + ni * 16)
                + *(const f32x4*)(av + ni * 16);
        *(f32x4*)(xo + ni * 16) = v;
      }
    }
  }
}

// ---------------- attn bias+mask precompute, in MFMA C-register layout ----------------
__global__ __launch_bounds__(64) void k_bias(const float* __restrict__ rpb,
                                             float* __restrict__ biasPk)
{
  const int blk = blockIdx.x;
  const int d = blk >> 5, cls = (blk >> 3) & 3, h = blk & 7;
  const int l = threadIdx.x, lo16 = l & 15, hg = l >> 4;
  const float* rp = rpb + (size_t)d * 225 * 8;
  float* ob = biasPk + (((size_t)d * 4 + cls) * 8 + h) * 4096;
#pragma unroll
  for (int mi = 0; mi < 4; ++mi)
#pragma unroll
    for (int ni = 0; ni < 4; ++ni)
#pragma unroll
      for (int j = 0; j < 4; ++j){
        int k = 16 * mi + 4 * hg + j, q = 16 * ni + lo16;
        int qr = q >> 3, qc = q & 7, kr = k >> 3, kc = k & 7;
        float v = rp[((qr - kr + 7) * 15 + (qc - kc + 7)) * 8 + h];
        if (d == 1){
          int lq = ((cls >> 1) ? (qr < 4 ? 1 : 2) : 0) * 3 + ((cls & 1) ? (qc < 4 ? 1 : 2) : 0);
          int lk = ((cls >> 1) ? (kr < 4 ? 1 : 2) : 0) * 3 + ((cls & 1) ? (kc < 4 ? 1 : 2) : 0);
          if (lq != lk) v -= 100.f;
        }
        ob[(mi * 4 + ni) * 256 + l * 4 + j] = v;
      }
}

// ---------------- window attention via MFMA: 1 wave per (window, head) ----------------
__global__ __launch_bounds__(64) void k_attn(
    const bfraw* __restrict__ qkv, const float* __restrict__ biasPk,
    bfraw* __restrict__ aout, int shift)
{
  __shared__ __align__(16) bfraw sV[64 * 32];   // [k][d]  4KB
  __shared__ __align__(16) bfraw sP[64 * 64];   // [q][k]  8KB, swizzled
  const int win = blockIdx.x >> 3, h = blockIdx.x & 7;
  const int b = win >> 6, wr = (win >> 3) & 7, wc = win & 7;
  const int l = threadIdx.x, lo16 = l & 15, hg = l >> 4;

  auto grow_of = [&](int n) -> size_t {
    int gi = (wr * 8 + (n >> 3) + shift) & 63;
    int gj = (wc * 8 + (n & 7) + shift) & 63;
    return ((size_t)b << 12) + gi * 64 + gj;
  };

  s16x8 vreg[4];
#pragma unroll
  for (int i = 0; i < 4; ++i){
    int row = i * 16 + (l >> 2);
    vreg[i] = *(const s16x8*)(qkv + grow_of(row) * 768 + 512 + h * 32 + (l & 3) * 8);
  }
#pragma unroll
  for (int i = 0; i < 4; ++i)
    *(s16x8*)&sV[i * 512 + l * 8] = vreg[i];

  s16x8 aK[4], bQ[4];
#pragma unroll
  for (int t = 0; t < 4; ++t){
    const bfraw* base = qkv + grow_of(16 * t + lo16) * 768 + h * 32 + hg * 8;
    bQ[t] = *(const s16x8*)base;
    aK[t] = *(const s16x8*)(base + 256);
  }

  f32x4 acc[4][4] = {};
#pragma unroll
  for (int mi = 0; mi < 4; ++mi)
#pragma unroll
    for (int ni = 0; ni < 4; ++ni)
      acc[mi][ni] = __builtin_amdgcn_mfma_f32_16x16x32_bf16(aK[mi], bQ[ni], acc[mi][ni], 0, 0, 0);

  const int cls = ((wr == 7) ? 2 : 0) | ((wc == 7) ? 1 : 0);
  const float* bb = biasPk + ((size_t)(cls * 8 + h)) * 4096;
#pragma unroll
  for (int mi = 0; mi < 4; ++mi)
#pragma unroll
    for (int ni = 0; ni < 4; ++ni){
      f32x4 bv4 = *(const f32x4*)(bb + (mi * 4 + ni) * 256 + l * 4);
      acc[mi][ni] = acc[mi][ni] * 0.17677669529663689f + bv4;
    }

#pragma unroll
  for (int ni = 0; ni < 4; ++ni){
    float m = acc[0][ni][0];
#pragma unroll
    for (int mi = 0; mi < 4; ++mi)
#pragma unroll
      for (int j = 0; j < 4; ++j) m = fmaxf(m, acc[mi][ni][j]);
    m = fmaxf(m, __shfl_xor(m, 16));
    m = fmaxf(m, __shfl_xor(m, 32));
    float s = 0.f;
#pragma unroll
    for (int mi = 0; mi < 4; ++mi)
#pragma unroll
      for (int j = 0; j < 4; ++j){
        float e = __expf(acc[mi][ni][j] - m);
        acc[mi][ni][j] = e; s += e;
      }
    s += __shfl_xor(s, 16);
    s += __shfl_xor(s, 32);
    float inv = 1.f / s;
#pragma unroll
    for (int mi = 0; mi < 4; ++mi)
#pragma unroll
      for (int j = 0; j < 4; ++j) acc[mi][ni][j] *= inv;
  }

#pragma unroll
  for (int mi = 0; mi < 4; ++mi)
#pragma unroll
    for (int ni = 0; ni < 4; ++ni){
      unsigned int w0, w1;
      asm("v_cvt_pk_bf16_f32 %0, %1, %2" : "=v"(w0) : "v"(acc[mi][ni][0]), "v"(acc[mi][ni][1]));
      asm("v_cvt_pk_bf16_f32 %0, %1, %2" : "=v"(w1) : "v"(acc[mi][ni][2]), "v"(acc[mi][ni][3]));
      int q = 16 * ni + lo16;
      int ad = (q * 128 + (16 * mi + 4 * hg) * 2) ^ ((q & 7) << 4);
      *(uint2*)((char*)sP + ad) = make_uint2(w0, w1);
    }

  asm volatile("s_waitcnt lgkmcnt(0)" ::: "memory");
  __builtin_amdgcn_sched_barrier(0);

  f32x4 opv[4][2] = {};
#pragma unroll
  for (int kt = 0; kt < 2; ++kt){
    s16x8 ap[4];
#pragma unroll
    for (int qi = 0; qi < 4; ++qi){
      int q = 16 * qi + lo16;
      int ad = (q * 128 + (kt * 32 + hg * 8) * 2) ^ ((q & 7) << 4);
      ap[qi] = *(const s16x8*)((const char*)sP + ad);
    }
    s16x8 vb[2];
#pragma unroll
    for (int nt = 0; nt < 2; ++nt)
#pragma unroll
      for (int e = 0; e < 8; ++e)
        vb[nt][e] = (short)sV[(kt * 32 + hg * 8 + e) * 32 + nt * 16 + lo16];
#pragma unroll
    for (int qi = 0; qi < 4; ++qi)
#pragma unroll
      for (int nt = 0; nt < 2; ++nt)
        opv[qi][nt] = __builtin_amdgcn_mfma_f32_16x16x32_bf16(ap[qi], vb[nt], opv[qi][nt], 0, 0, 0);
  }

  bfraw* ob = aout + ((size_t)win * 64) * 256 + h * 32 + lo16;
#pragma unroll
  for (int qi = 0; qi < 4; ++qi)
#pragma unroll
    for (int nt = 0; nt < 2; ++nt)
#pragma unroll
      for (int j = 0; j < 4; ++j)
        ob[(size_t)(16 * qi + 4 * hg + j) * 256 + nt * 16] = f2bbits(opv[qi][nt][j]);
}

// ---------------- cross-attn collapsed: addv[d][b][j] (Tk==1 => softmax==1, o==v) ----------------
__global__ __launch_bounds__(256) void k_addvec(
    const float* __restrict__ emb, const float* __restrict__ qw, const float* __restrict__ qb,
    const float* __restrict__ inw, const float* __restrict__ inb,
    const float* __restrict__ outw, const float* __restrict__ outb,
    float* __restrict__ addv)
{
  const int d = blockIdx.x >> 4, b = blockIdx.x & 15;
  const int j = threadIdx.x;
  __shared__ float sc[256], sv[256];
  float a = qb[j];
  for (int k = 0; k < 512; ++k) a = fmaf(emb[b * 512 + k], qw[k * 256 + j], a);
  sc[j] = a; __syncthreads();
  float v = inb[d * 768 + 512 + j];
  const float* wrp = inw + (size_t)d * 768 * 256 + (size_t)(512 + j) * 256;
  for (int k = 0; k < 256; ++k) v = fmaf(sc[k], wrp[k], v);
  sv[j] = v; __syncthreads();
  float o = outb[d * 256 + j];
  const float* wop = outw + (size_t)d * 65536 + (size_t)j * 256;
  for (int k = 0; k < 256; ++k) o = fmaf(sv[k], wop[k], o);
  addv[(size_t)(d * 16 + b) * 256 + j] = o;
}

extern "C" void kernel_launch(void* const* d_in, const int* in_sizes, int n_in,
                              void* d_out, int out_size, void* d_ws, size_t ws_size,
                              hipStream_t stream)
{
  (void)in_sizes; (void)n_in; (void)out_size; (void)ws_size;
  const float* x_in     = (const float*)d_in[0];
  const float* emb      = (const float*)d_in[1];
  const float* qenc_w   = (const float*)d_in[2];
  const float* qenc_b   = (const float*)d_in[3];
  const float* n1_g     = (const float*)d_in[4];
  const float* n1_b     = (const float*)d_in[5];
  const float* qkv_w    = (const float*)d_in[6];
  const float* qkv_b    = (const float*)d_in[7];
  const float* rpb      = (const float*)d_in[8];
  const float* proj_w   = (const float*)d_in[9];
  const float* proj_b   = (const float*)d_in[10];
  const float* n2_g     = (const float*)d_in[11];
  const float* n2_b     = (const float*)d_in[12];
  const float* fc1_w    = (const float*)d_in[13];
  const float* fc1_b    = (const float*)d_in[14];
  const float* fc2_w    = (const float*)d_in[15];
  const float* fc2_b    = (const float*)d_in[16];
  const float* ca_in_w  = (const float*)d_in[19];
  const float* ca_in_b  = (const float*)d_in[20];
  const float* ca_out_w = (const float*)d_in[21];
  const float* ca_out_b = (const float*)d_in[22];

  float* xfp  = (float*)d_out;                           // fp32 residual == output
  char* ws = (char*)d_ws;
  bfraw* ybuf = (bfraw*)ws;                              // 32MB bf16
  bfraw* qkvb = (bfraw*)(ws + ((size_t)32 << 20));       // 128MB (qkv 96MB, then h1)
  bfraw* wT   = (bfraw*)(ws + ((size_t)160 << 20));
  float* biasPk = (float*)(ws + ((size_t)166 << 20));    // [2][4][8][4096] f32 = 1MB

  bfraw *qkvT[2], *projT[2], *fc1T[2], *fc2T[2];
  size_t off = 0;
  for (int d = 0; d < 2; ++d){ qkvT[d] = wT + off; off += 768 * 256; }
  for (int d = 0; d < 2; ++d){ projT[d] = wT + off; off += 256 * 256; }
  for (int d = 0; d < 2; ++d){ fc1T[d] = wT + off; off += 1024 * 256; }
  for (int d = 0; d < 2; ++d){ fc2T[d] = wT + off; off += 256 * 1024; }
  float* addv = (float*)(wT + ((off + 1) & ~(size_t)1)); // [2][16][256] fp32

  for (int d = 0; d < 2; ++d){
    k_tr<<<(256 * 768  + 255) / 256, 256, 0, stream>>>(qkv_w  + (size_t)d * 256 * 768,  qkvT[d], 256, 768);
    k_tr<<<(256 * 256  + 255) / 256, 256, 0, stream>>>(proj_w + (size_t)d * 256 * 256,  projT[d], 256, 256);
    k_tr<<<(256 * 1024 + 255) / 256, 256, 0, stream>>>(fc1_w  + (size_t)d * 256 * 1024, fc1T[d], 256, 1024);
    k_tr<<<(1024 * 256 + 255) / 256, 256, 0, stream>>>(fc2_w  + (size_t)d * 1024 * 256, fc2T[d], 1024, 256);
  }
  k_bias<<<64, 64, 0, stream>>>(rpb, biasPk);
  k_addvec<<<32, 256, 0, stream>>>(emb, qenc_w, qenc_b, ca_in_w, ca_in_b, ca_out_w, ca_out_b, addv);

  for (int d = 0; d < 2; ++d){
    const int shift = d ? 4 : 0;
    const float* resid_in = d ? (const float*)xfp : x_in;
    k_ln<<<16384, 256, 0, stream>>>(resid_in, n1_g + d * 256, n1_b + d * 256, ybuf);
    k_gemm<0><<<512 * 6, 256, 0, stream>>>(ybuf, qkvT[d], qkv_b + d * 768, qkvb, 768,
                                           nullptr, nullptr, nullptr, 65536, 768, 256, 0);
    k_attn<<<8192, 64, 0, stream>>>(qkvb, biasPk + (size_t)d * 4 * 8 * 4096, ybuf, shift);
    k_gemm<2><<<512 * 2, 256, 0, stream>>>(ybuf, projT[d], proj_b + d * 256, nullptr, 0,
                                           xfp, resid_in, nullptr, 65536, 256, 256, shift);
    k_ln<<<16384, 256, 0, stream>>>(xfp, n2_g + d * 256, n2_b + d * 256, ybuf);
    k_gemm<1><<<512 * 8, 256, 0, stream>>>(ybuf, fc1T[d], fc1_b + d * 1024, qkvb, 1024,
                                           nullptr, nullptr, nullptr, 65536, 1024, 256, 0);
    k_gemm<3><<<512 * 2, 256, 0, stream>>>(qkvb, fc2T[d], fc2_b + d * 256, nullptr, 0,
                                           xfp, nullptr, addv + (size_t)d * 16 * 256,
                                           65536, 256, 1024, 0);
  }
}